// Round 13
// baseline (226.443 us; speedup 1.0000x reference)
//
#include <hip/hip_runtime.h>

// GCN layer: out = relu(x @ W_self^T + b_self + segment_mean(x[src], dst) @ W_neigh^T)
// N = 100000 nodes, D = 64, E = 1.25M edges.
//
// Pipeline (4 kernels):
//   x2bf        : x fp32 -> bf16 (12.8 MB data plane); block 0 also inits
//                 bucket cursors to b*CAP (fixed-capacity buckets, no hist/scan).
//   bin_scatter : LDS-staged radix scatter into 782 buckets of 128 dst-nodes;
//                 block-local int-LDS hist + scan + contiguous run claim ->
//                 full-line writes (no cross-XCD partial-line churn).
//   csr_gather  : FUSED csr+gather. One block per bucket (782 = ~3/CU, all
//                 co-resident): window -> LDS node-sorted scol (int atomics
//                 only! LDS fp32 atomicAdd is a CAS loop on gfx950 — r3/r11
//                 ~500us disasters) -> half-wave per node, lane k owns packed
//                 dims {2k,2k+1}: one coalesced 128B bf16 row load + 4 VALU per
//                 edge, NO shuffles, mean folded into packed bf16 write.
//   gcn_gemm    : bf16 MFMA (16x16x32), zero LDS; A-frags straight from bf16
//                 xb/aggb; W packed from fp32 (L1-hot); bias+relu fused.

#define BKSH 7                // log2(nodes per bucket)
#define BKN 128               // nodes per bucket
#define CAP 2048              // edge capacity per bucket (mean 1598, +11 sigma; r11-validated)
#define CHUNK 4096            // edges per scatter block
#define SCANN 1024            // scatter scan width (>= NBK = 782)

typedef __attribute__((ext_vector_type(8))) short short8;
typedef __attribute__((ext_vector_type(4))) float floatx4;

// fp32 -> bf16 round-to-nearest-even, branch-free.
static __device__ inline unsigned int f2bf(float f) {
  union { float f; unsigned int u; } v;
  v.f = f;
  unsigned int r = v.u + 0x7FFFu + ((v.u >> 16) & 1u);
  return r >> 16;
}

static __device__ inline short8 pack8(float4 a, float4 b) {
  short8 s;
  s[0] = (short)f2bf(a.x); s[1] = (short)f2bf(a.y);
  s[2] = (short)f2bf(a.z); s[3] = (short)f2bf(a.w);
  s[4] = (short)f2bf(b.x); s[5] = (short)f2bf(b.y);
  s[6] = (short)f2bf(b.z); s[7] = (short)f2bf(b.w);
  return s;
}

__global__ __launch_bounds__(256) void x2bf(const float* __restrict__ x,
                                            unsigned short* __restrict__ xb,
                                            int* __restrict__ cursor,
                                            long long n, int NBK) {
  long long i = ((long long)blockIdx.x * 256 + threadIdx.x) * 8;
  if (i < n) {
    float4 a = *(const float4*)&x[i];
    float4 b = *(const float4*)&x[i + 4];
    *(short8*)&xb[i] = pack8(a, b);
  }
  if (blockIdx.x == 0) {
    for (int j = threadIdx.x; j < NBK; j += 256) cursor[j] = j * CAP;
  }
}

// LDS-staged radix scatter into fixed-capacity bucket regions (782 buckets).
__global__ __launch_bounds__(256) void bin_scatter(const int* __restrict__ src,
                                                   const int* __restrict__ dst,
                                                   int* __restrict__ cursor,
                                                   int* __restrict__ ebuf,
                                                   int E, int NBK) {
  __shared__ int h[SCANN], loff[SCANN], gbase[SCANN];
  __shared__ int sbuf[CHUNK];
  __shared__ int wsum[4];
  int t = threadIdx.x;
  for (int i = t; i < SCANN; i += 256) h[i] = 0;
  __syncthreads();

  int base = blockIdx.x * CHUNK;
  int myd[CHUNK / 256], mys[CHUNK / 256];
#pragma unroll
  for (int i = 0; i < CHUNK / 256; ++i) {
    int e = base + t + 256 * i;  // coalesced
    if (e < E) {
      myd[i] = dst[e];
      mys[i] = src[e];
      atomicAdd(&h[myd[i] >> BKSH], 1);   // LDS int atomic: native, fast
    } else myd[i] = -1;
  }
  __syncthreads();

  // block exclusive scan of h[0..1023] (4 entries per thread)
  {
    int i0 = t * 4;
    int v0 = h[i0], v1 = h[i0 + 1], v2 = h[i0 + 2], v3 = h[i0 + 3];
    int tot = v0 + v1 + v2 + v3;
    int lane = t & 63, w = t >> 6;
    int inc = tot;
#pragma unroll
    for (int o = 1; o < 64; o <<= 1) {
      int u = __shfl_up(inc, o, 64);
      if (lane >= o) inc += u;
    }
    if (lane == 63) wsum[w] = inc;
    __syncthreads();
    int wex = 0;
    for (int i = 0; i < w; ++i) wex += wsum[i];
    int ex = wex + inc - tot;
    loff[i0] = ex; loff[i0 + 1] = ex + v0;
    loff[i0 + 2] = ex + v0 + v1; loff[i0 + 3] = ex + v0 + v1 + v2;
  }
  __syncthreads();

  // claim contiguous runs in fixed bucket regions; reuse h as local cursor
  for (int b = t; b < SCANN; b += 256) {
    if (b < NBK && h[b] > 0) gbase[b] = atomicAdd(&cursor[b], h[b]);
    h[b] = 0;
  }
  __syncthreads();

#pragma unroll
  for (int i = 0; i < CHUNK / 256; ++i) {
    if (myd[i] >= 0) {
      int b = myd[i] >> BKSH;
      int p = atomicAdd(&h[b], 1);
      sbuf[loff[b] + p] = mys[i] | ((myd[i] & (BKN - 1)) << 17);  // src < 2^17
    }
  }
  __syncthreads();

  // stream each (block,bucket) run out contiguously
  int w = t >> 6, lane = t & 63;
  for (int b = w; b < NBK; b += 4) {
    int c = h[b], lo = loff[b], go = gbase[b];
    for (int j = lane; j < c; j += 64)
      ebuf[go + j] = sbuf[lo + j];
  }
}

// Fused CSR + gather. One 256-thread block per 128-node bucket.
// Phase 1: count + scan + node-sort window into LDS scol (int atomics only).
// Phase 2: half-wave per node; lane k owns packed dims {2k,2k+1}; one coalesced
// dword load per edge per lane (128B bf16 row per half-wave), fp32 accumulate,
// no cross-lane reduce; mean folded into packed bf16 dword write.
__global__ __launch_bounds__(256) void csr_gather(const unsigned short* __restrict__ xb,
                                                  const int* __restrict__ cursor,
                                                  const int* __restrict__ ebuf,
                                                  unsigned short* __restrict__ aggb,
                                                  int N) {
  __shared__ int scol[CAP];
  __shared__ int cnt[BKN], off[BKN + 1];
  int b = blockIdx.x, t = threadIdx.x;
  int s = b * CAP;
  int m = cursor[b] - s;        // edges in this bucket

  if (t < BKN) cnt[t] = 0;
  __syncthreads();
  for (int j = t; j < m; j += 256)
    atomicAdd(&cnt[(ebuf[s + j] >> 17) & (BKN - 1)], 1);
  __syncthreads();

  if (t < 64) {  // wave 0: exclusive scan of cnt[0..127]
    int i0 = 2 * t, i1 = 2 * t + 1;
    int v0 = cnt[i0], v1 = cnt[i1];
    int ss = v0 + v1, inc = ss;
#pragma unroll
    for (int o = 1; o < 64; o <<= 1) {
      int u = __shfl_up(inc, o, 64);
      if (t >= o) inc += u;
    }
    int ex = inc - ss;
    off[i0] = ex; off[i1] = ex + v0;
    if (t == 63) off[BKN] = m;
  }
  __syncthreads();
  if (t < BKN) cnt[t] = 0;  // reuse as cursor
  __syncthreads();
  for (int j = t; j < m; j += 256) {
    int v = ebuf[s + j];
    int nl = (v >> 17) & (BKN - 1);
    int p = atomicAdd(&cnt[nl], 1);
    scol[off[nl] + p] = v & 0x1FFFF;
  }
  __syncthreads();

  // gather: wave w, half-wave h -> node-pair p = w, w+4, ...; node n = 2p+h
  const unsigned int* xw = (const unsigned int*)xb;
  unsigned int* aw = (unsigned int*)aggb;
  int lane = t & 63, w = t >> 6;
  int h = lane >> 5, k = lane & 31;
  int nbase = b << BKSH;

  for (int p = w; p < BKN / 2; p += 4) {
    int n = 2 * p + h;
    int node = nbase + n;
    if (node >= N) continue;
    int cs = off[n], ce = off[n + 1];
    float f0 = 0.f, f1 = 0.f, g0 = 0.f, g1 = 0.f;
    int j = cs;
    for (; j + 1 < ce; j += 2) {  // 2 independent row loads in flight
      int s0 = scol[j], s1 = scol[j + 1];        // half-wave broadcast LDS read
      unsigned int d0 = xw[s0 * 32 + k];         // 32 lanes x 4B = 128B row
      unsigned int d1 = xw[s1 * 32 + k];
      f0 += __uint_as_float(d0 << 16);
      f1 += __uint_as_float(d0 & 0xFFFF0000u);
      g0 += __uint_as_float(d1 << 16);
      g1 += __uint_as_float(d1 & 0xFFFF0000u);
    }
    if (j < ce) {
      unsigned int d0 = xw[scol[j] * 32 + k];
      f0 += __uint_as_float(d0 << 16);
      f1 += __uint_as_float(d0 & 0xFFFF0000u);
    }
    f0 += g0; f1 += g1;
    float inv = 1.0f / fmaxf((float)(ce - cs), 1.0f);
    unsigned int pkd = (f2bf(f1 * inv) << 16) | f2bf(f0 * inv);
    aw[(long long)node * 32 + k] = pkd;          // coalesced 128B
  }
}

// bf16 MFMA GEMM, zero LDS. Wave w owns nodes [blk*64 + w*16, +16).
// A-frags load DIRECTLY from bf16 arrays; B-frags packed from fp32 W (L1-hot).
// One accumulator: D = Ax*Ws^T + Aagg*Wn^T. C/D: col=lane&15, row=quad*4+reg.
__global__ __launch_bounds__(256) void gcn_gemm(const unsigned short* __restrict__ xb,
                                                const unsigned short* __restrict__ aggb,
                                                const float* __restrict__ Wself,
                                                const float* __restrict__ bself,
                                                const float* __restrict__ Wneigh,
                                                float* __restrict__ out, int N) {
  int lane = threadIdx.x & 63;
  int w = threadIdx.x >> 6;
  int tb = blockIdx.x * 64 + w * 16;
  int m = lane & 15, q = lane >> 4;

  long long rowA = (long long)min(tb + m, N - 1) * 64;
  short8 ax[2], aa[2];
#pragma unroll
  for (int ks = 0; ks < 2; ++ks) {
    ax[ks] = *(const short8*)&xb[rowA + ks * 32 + q * 8];
    aa[ks] = *(const short8*)&aggb[rowA + ks * 32 + q * 8];
  }

#pragma unroll
  for (int nt = 0; nt < 4; ++nt) {
    int ob = nt * 16;
    long long rowB = (long long)(ob + m) * 64;
    floatx4 acc = {0.f, 0.f, 0.f, 0.f};
#pragma unroll
    for (int ks = 0; ks < 2; ++ks) {
      const float* pw = &Wself[rowB + ks * 32 + q * 8];
      short8 bw = pack8(*(const float4*)pw, *(const float4*)(pw + 4));
      acc = __builtin_amdgcn_mfma_f32_16x16x32_bf16(ax[ks], bw, acc, 0, 0, 0);
      const float* pn = &Wneigh[rowB + ks * 32 + q * 8];
      short8 bn = pack8(*(const float4*)pn, *(const float4*)(pn + 4));
      acc = __builtin_amdgcn_mfma_f32_16x16x32_bf16(aa[ks], bn, acc, 0, 0, 0);
    }
    float bias = bself[ob + m];
#pragma unroll
    for (int r = 0; r < 4; ++r) {
      int node = tb + q * 4 + r;
      if (node < N) {
        float v = acc[r] + bias;
        out[(long long)node * 64 + ob + m] = fmaxf(v, 0.f);
      }
    }
  }
}

extern "C" void kernel_launch(void* const* d_in, const int* in_sizes, int n_in,
                              void* d_out, int out_size, void* d_ws, size_t ws_size,
                              hipStream_t stream) {
  const float* x      = (const float*)d_in[0];
  const int*   eidx   = (const int*)d_in[1];
  const float* Wself  = (const float*)d_in[2];
  const float* bself  = (const float*)d_in[3];
  const float* Wneigh = (const float*)d_in[4];
  float* out = (float*)d_out;

  const int N = in_sizes[0] / 64;
  const int E = in_sizes[1] / 2;
  const int* src = eidx;      // edge_index row 0
  const int* dst = eidx + E;  // edge_index row 1
  const int NBK = (N + BKN - 1) / BKN;  // 782 buckets of 128 nodes

  // ws layout: xb[N*64] bf16 | aggb[N*64] bf16 | cursor[pad 1024] | ebuf[NBK*CAP]
  unsigned short* xb   = (unsigned short*)d_ws;
  unsigned short* aggb = xb + (size_t)N * 64;
  int* cursor = (int*)(aggb + (size_t)N * 64);
  int* ebuf   = cursor + SCANN;

  long long nx = (long long)N * 64;
  x2bf<<<(int)((nx / 8 + 255) / 256), 256, 0, stream>>>(x, xb, cursor, nx, NBK);

  int cb = (E + CHUNK - 1) / CHUNK;  // 306 scatter blocks
  bin_scatter<<<cb, 256, 0, stream>>>(src, dst, cursor, ebuf, E, NBK);
  csr_gather<<<NBK, 256, 0, stream>>>(xb, cursor, ebuf, aggb, N);
  gcn_gemm<<<(N + 63) / 64, 256, 0, stream>>>(xb, aggb, Wself, bself, Wneigh, out, N);
}